// Round 2
// baseline (459.869 us; speedup 1.0000x reference)
//
#include <hip/hip_runtime.h>

namespace {

constexpr int KFS = 51;
constexpr int NB = 2, NC = 3, HH = 512, WW = 512;
constexpr int HP = HH + KFS - 1;   // 562
constexpr int WP = WW + KFS - 1;   // 562
constexpr int TW = 128;            // output tile width
constexpr int TH = 8;              // output tile height
constexpr int PX = 4;              // pixels per thread along x
constexpr int NTX = TW / PX;       // 32
constexpr int NTHREADS = NTX * TH; // 256
constexpr int RB = TH + 2;         // rolling buffer rows (10)
constexpr int TILEW = TW + KFS - 1;  // 178 valid cols
constexpr int LDSW = 186;            // row stride: 186 mod 4 == 2 -> half-waves on disjoint bank residues
constexpr int NROWS = TH + KFS - 1;  // 58 input rows per tile
constexpr int NSTAGE = 3;            // ceil(3*178 / 256)
constexpr int CSTRIDE = RB * LDSW;   // floats per channel block (1860)
constexpr int ROWB = LDSW;           // float stride per slot

struct Stager {
  const float* g[NSTAGE];  // points at tile-relative row 0 of this thread's element
  int lbase[NSTAGE];       // c*CSTRIDE + col (dword index, slot excluded)
  bool act[NSTAGE];
};

// One pass over taps j = JC .. JC+J-1 with the h-chunk in registers.
// NF2 = number of float2 LDS reads per (row, channel).
template <int JC, int J, int NF2>
__device__ __forceinline__ void run_pass(float* __restrict__ lds, const Stager& st,
                                         const float* __restrict__ v2,
                                         const float* __restrict__ h3,
                                         float (&acc)[NC][PX],
                                         int y, int x0, int tx, int ty) {
  // Prologue: stage tile-relative rows 0..RB-2.
  #pragma unroll 1
  for (int r = 0; r < RB - 1; ++r) {
    #pragma unroll
    for (int k = 0; k < NSTAGE; ++k)
      if (st.act[k]) lds[st.lbase[k] + r * ROWB] = st.g[k][(size_t)r * WP];
  }
  __syncthreads();

  // h chunk: h4[j] = h3[JC+j, y, x0..x0+3]
  float4 h4[J];
  #pragma unroll
  for (int j = 0; j < J; ++j)
    h4[j] = *reinterpret_cast<const float4*>(h3 + ((size_t)(JC + j) * HH + y) * WW + x0);

  // rolling offsets (float index of slot base)
  int rdoff = ty * ROWB;             // slot (ty+i) % RB
  int stoff = (RB - 1) * ROWB;       // slot (i+RB-1) % RB
  const float* gp[NSTAGE];
  #pragma unroll
  for (int k = 0; k < NSTAGE; ++k) gp[k] = st.g[k] + (size_t)(RB - 1) * WP;

  #pragma unroll 1
  for (int i = 0; i < KFS; ++i) {
    const int rn = i + RB - 1;
    const bool do_stage = (rn < NROWS);
    float sv[NSTAGE];
    if (do_stage) {
      #pragma unroll
      for (int k = 0; k < NSTAGE; ++k) sv[k] = st.act[k] ? gp[k][0] : 0.f;
    }

    const float4 v4 = *reinterpret_cast<const float4*>(v2 + ((size_t)i * HH + y) * WW + x0);

    #pragma unroll
    for (int c = 0; c < NC; ++c) {
      // window floats [4tx+JC .. 4tx+JC+2*NF2-1] of row (ty+i), channel c
      const float2* wp = reinterpret_cast<const float2*>(lds + c * CSTRIDE + rdoff)
                         + (2 * tx + JC / 2);
      float w[2 * NF2];
      #pragma unroll
      for (int k = 0; k < NF2; ++k) {
        const float2 q = wp[k];
        w[2 * k] = q.x;
        w[2 * k + 1] = q.y;
      }
      float hz0 = 0.f, hz1 = 0.f, hz2 = 0.f, hz3 = 0.f;
      #pragma unroll
      for (int j = 0; j < J; ++j) {
        hz0 = fmaf(w[j + 0], h4[j].x, hz0);
        hz1 = fmaf(w[j + 1], h4[j].y, hz1);
        hz2 = fmaf(w[j + 2], h4[j].z, hz2);
        hz3 = fmaf(w[j + 3], h4[j].w, hz3);
      }
      acc[c][0] = fmaf(v4.x, hz0, acc[c][0]);
      acc[c][1] = fmaf(v4.y, hz1, acc[c][1]);
      acc[c][2] = fmaf(v4.z, hz2, acc[c][2]);
      acc[c][3] = fmaf(v4.w, hz3, acc[c][3]);
    }

    if (do_stage) {
      #pragma unroll
      for (int k = 0; k < NSTAGE; ++k)
        if (st.act[k]) lds[st.lbase[k] + stoff] = sv[k];
      #pragma unroll
      for (int k = 0; k < NSTAGE; ++k) gp[k] += WP;
    }
    __syncthreads();

    rdoff += ROWB; if (rdoff == RB * ROWB) rdoff = 0;
    stoff += ROWB; if (stoff == RB * ROWB) stoff = 0;
  }
}

__global__ __launch_bounds__(NTHREADS)
void sepconv_kernel(const float* __restrict__ in1, const float* __restrict__ in2,
                    const float* __restrict__ in3, float* __restrict__ out) {
  __shared__ __align__(16) float lds[NC * CSTRIDE];

  const int t = threadIdx.x;
  const int tx = t & (NTX - 1);
  const int ty = t >> 5;
  const int x0t = blockIdx.x * TW;
  const int y0t = blockIdx.y * TH;
  const int b = blockIdx.z;
  const int x0 = x0t + tx * PX;
  const int y = y0t + ty;

  const float* in1b = in1 + (size_t)b * NC * HP * WP;
  const float* v2 = in2 + (size_t)b * KFS * HH * WW;
  const float* h3 = in3 + (size_t)b * KFS * HH * WW;

  // Precompute staging assignments (once).
  Stager st;
  #pragma unroll
  for (int k = 0; k < NSTAGE; ++k) {
    const int e = t + k * NTHREADS;
    st.act[k] = (e < NC * TILEW);
    const int ec = st.act[k] ? e : (NC * TILEW - 1);
    const int c = ec / TILEW;
    const int col = ec - c * TILEW;
    st.g[k] = in1b + ((size_t)c * HP + y0t) * WP + x0t + col;
    st.lbase[k] = c * CSTRIDE + col;
  }

  float acc[NC][PX];
  #pragma unroll
  for (int c = 0; c < NC; ++c)
    #pragma unroll
    for (int p = 0; p < PX; ++p) acc[c][p] = 0.f;

  run_pass<0, 28, 16>(lds, st, v2, h3, acc, y, x0, tx, ty);
  run_pass<28, 23, 13>(lds, st, v2, h3, acc, y, x0, tx, ty);

  float* outb = out + (size_t)b * NC * HH * WW;
  #pragma unroll
  for (int c = 0; c < NC; ++c) {
    float4 o;
    o.x = acc[c][0]; o.y = acc[c][1]; o.z = acc[c][2]; o.w = acc[c][3];
    *reinterpret_cast<float4*>(outb + ((size_t)c * HH + y) * WW + x0) = o;
  }
}

}  // namespace

extern "C" void kernel_launch(void* const* d_in, const int* in_sizes, int n_in,
                              void* d_out, int out_size, void* d_ws, size_t ws_size,
                              hipStream_t stream) {
  const float* in1 = (const float*)d_in[0];
  const float* in2 = (const float*)d_in[1];
  const float* in3 = (const float*)d_in[2];
  float* out = (float*)d_out;

  dim3 grid(WW / TW, HH / TH, NB);
  sepconv_kernel<<<grid, NTHREADS, 0, stream>>>(in1, in2, in3, out);
}

// Round 3
// 181.947 us; speedup vs baseline: 2.5275x; 2.5275x over previous
//
#include <hip/hip_runtime.h>

namespace {

constexpr int KFS = 51;
constexpr int NB = 2, NC = 3, HH = 512, WW = 512;
constexpr int HP = HH + KFS - 1;   // 562
constexpr int WP = WW + KFS - 1;   // 562
constexpr int TW = 128;            // output tile width
constexpr int TH = 8;              // output tile height
constexpr int PX = 4;              // pixels per thread
constexpr int NTX = TW / PX;       // 32
constexpr int NTHREADS = NTX * TH; // 256
constexpr int TILEW = TW + KFS - 1;  // 178 input cols per tile
constexpr int NROWS = TH + KFS - 1;  // 58 input rows per tile
constexpr int SUBW = 45;             // sub-array stride (ceil(178/4))
constexpr int ROWDW = 4 * SUBW;      // 180 dwords per LDS row
constexpr int JCH = 17;              // taps per pass (3 passes x 17 = 51)
constexpr int NW = JCH + PX - 1;     // 20 window dwords per (i, pass)

// De-interleaved position of column c within a row: stride-1 across lanes.
__device__ __forceinline__ int pmap(int c) { return (c & 3) * SUBW + (c >> 2); }

template <int JC>
__device__ __forceinline__ void run_pass(const float* __restrict__ lds,
                                         const float* __restrict__ v2,
                                         const float* __restrict__ h3,
                                         float (&acc)[PX],
                                         int y, int x0, int tx, int ty) {
  // h-chunk for this thread's 4 pixels (resident across the i-loop).
  float4 h4[JCH];
  #pragma unroll
  for (int j = 0; j < JCH; ++j)
    h4[j] = *reinterpret_cast<const float4*>(h3 + ((size_t)(JC + j) * HH + y) * WW + x0);

  const float* vp = v2 + (size_t)y * WW + x0;
  int rb = ty * ROWDW + tx;  // lane dword base for row ty (+i per iteration)

  #pragma unroll 2
  for (int i = 0; i < KFS; ++i) {
    const float4 v4 = *reinterpret_cast<const float4*>(vp);

    // Window: cols 4*tx+JC .. 4*tx+JC+NW-1 of row ty+i.
    // Address = rb + uniform-constant  ->  stride-1 per phase, conflict-free,
    // constants fold into ds_read immediates.
    float w[NW];
    #pragma unroll
    for (int k = 0; k < NW; ++k)
      w[k] = lds[rb + (((JC + k) & 3) * SUBW + ((JC + k) >> 2))];

    float hz0 = 0.f, hz1 = 0.f, hz2 = 0.f, hz3 = 0.f;
    #pragma unroll
    for (int j = 0; j < JCH; ++j) {
      hz0 = fmaf(w[j + 0], h4[j].x, hz0);
      hz1 = fmaf(w[j + 1], h4[j].y, hz1);
      hz2 = fmaf(w[j + 2], h4[j].z, hz2);
      hz3 = fmaf(w[j + 3], h4[j].w, hz3);
    }
    acc[0] = fmaf(v4.x, hz0, acc[0]);
    acc[1] = fmaf(v4.y, hz1, acc[1]);
    acc[2] = fmaf(v4.z, hz2, acc[2]);
    acc[3] = fmaf(v4.w, hz3, acc[3]);

    rb += ROWDW;
    vp += (size_t)HH * WW;
  }
}

__global__ __launch_bounds__(NTHREADS, 3)
void sepconv_kernel(const float* __restrict__ in1, const float* __restrict__ in2,
                    const float* __restrict__ in3, float* __restrict__ out) {
  __shared__ float tile[NROWS * ROWDW];  // 41,760 B: one channel, whole tile

  const int t = threadIdx.x;
  const int tx = t & (NTX - 1);
  const int ty = t >> 5;
  const int x0t = blockIdx.x * TW;
  const int y0t = blockIdx.y * TH;
  const int z = blockIdx.z;        // z = b*NC + c
  const int b = z / NC;
  const int c = z - b * NC;
  const int x0 = x0t + tx * PX;
  const int y = y0t + ty;

  const float* in1c = in1 + (size_t)(b * NC + c) * HP * WP;
  const float* v2 = in2 + (size_t)b * KFS * HH * WW;
  const float* h3 = in3 + (size_t)b * KFS * HH * WW;

  // Stage the whole channel tile once (float2 global loads, de-interleaved stores).
  constexpr int N2 = NROWS * (TILEW / 2);  // 58 * 89 = 5162
  for (int e2 = t; e2 < N2; e2 += NTHREADS) {
    const int row = e2 / (TILEW / 2);
    const int c2 = e2 - row * (TILEW / 2);
    const int col = 2 * c2;
    const float2 q = *reinterpret_cast<const float2*>(
        in1c + (size_t)(y0t + row) * WP + x0t + col);
    tile[row * ROWDW + pmap(col)] = q.x;
    tile[row * ROWDW + pmap(col + 1)] = q.y;
  }
  __syncthreads();

  float acc[PX] = {0.f, 0.f, 0.f, 0.f};
  run_pass<0>(tile, v2, h3, acc, y, x0, tx, ty);
  run_pass<17>(tile, v2, h3, acc, y, x0, tx, ty);
  run_pass<34>(tile, v2, h3, acc, y, x0, tx, ty);

  float4 o;
  o.x = acc[0]; o.y = acc[1]; o.z = acc[2]; o.w = acc[3];
  *reinterpret_cast<float4*>(out + ((size_t)(b * NC + c) * HH + y) * WW + x0) = o;
}

}  // namespace

extern "C" void kernel_launch(void* const* d_in, const int* in_sizes, int n_in,
                              void* d_out, int out_size, void* d_ws, size_t ws_size,
                              hipStream_t stream) {
  const float* in1 = (const float*)d_in[0];
  const float* in2 = (const float*)d_in[1];
  const float* in3 = (const float*)d_in[2];
  float* out = (float*)d_out;

  dim3 grid(WW / TW, HH / TH, NB * NC);
  sepconv_kernel<<<grid, NTHREADS, 0, stream>>>(in1, in2, in3, out);
}

// Round 4
// 121.580 us; speedup vs baseline: 3.7824x; 1.4965x over previous
//
#include <hip/hip_runtime.h>
#include <cstdint>

namespace {

typedef _Float16 half2v __attribute__((ext_vector_type(2)));

constexpr int KFS = 51;
constexpr int NB = 2, NC = 3, HH = 512, WW = 512;
constexpr int HP = HH + KFS - 1;   // 562
constexpr int WP = WW + KFS - 1;   // 562
constexpr int TW = 128, TH = 8, PX = 4;
constexpr int NTX = TW / PX;          // 32
constexpr int NTHREADS = NTX * TH;    // 256
constexpr int TILEW = TW + KFS - 1;   // 178 input cols per tile
constexpr int NROWS = TH + KFS - 1;   // 58 input rows per tile
constexpr int QPR = TILEW / 2;        // 89 f16-pairs per row
constexpr int PAIRS = 90;             // row stride in dwords
constexpr int CTILE = NROWS * PAIRS;  // 5220 dwords per channel
constexpr size_t VSTR = (size_t)HH * WW;

__device__ __forceinline__ uint32_t pack2(float a, float b) {
  half2v p;
  p.x = (_Float16)a;  // RNE
  p.y = (_Float16)b;
  return __builtin_bit_cast(uint32_t, p);
}

__device__ __forceinline__ float fdot2(uint32_t a, uint32_t b, float c) {
#if defined(__has_builtin) && __has_builtin(__builtin_amdgcn_fdot2)
  return __builtin_amdgcn_fdot2(__builtin_bit_cast(half2v, a),
                                __builtin_bit_cast(half2v, b), c, false);
#else
  float r;
  asm("v_dot2_f32_f16 %0, %1, %2, %3" : "=v"(r) : "v"(a), "v"(b), "v"(c));
  return r;
#endif
}

// Pass over taps j = JC..JC+J-1 (JC even). Window pairs ev[k] = (w[2k], w[2k+1])
// relative to col base 4*tx+JC. Pixel p needs w[p+j]*h_p[j]:
//   p=0: ev[k] . (hx[2k],   hx[2k+1])  = heX[k]
//   p=1: ev[k] . (hy[2k-1], hy[2k])    = hmY[k]
//   p=2: ev[k] . (hz[2k-2], hz[2k-1])  = heZ[k-1]
//   p=3: ev[k] . (hw[2k-3], hw[2k-2])  = hmW[k-1]
template <int JC, int J>
__device__ __forceinline__ void run_pass(const uint32_t* __restrict__ tile,
                                         const float* __restrict__ v2,
                                         const float* __restrict__ h3,
                                         float (&acc)[NC][PX],
                                         int y, int x0, int tx, int ty) {
  constexpr int NHE = (J + 1) / 2;
  constexpr int NHM = (J + 2) / 2;
  constexpr int NEV = (J + 4) / 2;
  constexpr int QC = JC / 2;

  // Build packed h registers (once per pass; h values beyond the chunk are 0).
  float4 hb[J];
  #pragma unroll
  for (int j = 0; j < J; ++j)
    hb[j] = *reinterpret_cast<const float4*>(h3 + ((size_t)(JC + j) * HH + y) * WW + x0);

  uint32_t heX[NHE], heZ[NHE], hmY[NHM], hmW[NHM];
  #pragma unroll
  for (int k = 0; k < NHE; ++k) {
    const float ax = hb[2 * k].x, az = hb[2 * k].z;
    const float bx = (2 * k + 1 < J) ? hb[2 * k + 1].x : 0.f;
    const float bz = (2 * k + 1 < J) ? hb[2 * k + 1].z : 0.f;
    heX[k] = pack2(ax, bx);
    heZ[k] = pack2(az, bz);
  }
  #pragma unroll
  for (int k = 0; k < NHM; ++k) {
    const float ay = (2 * k - 1 >= 0) ? hb[2 * k - 1].y : 0.f;
    const float aw = (2 * k - 1 >= 0) ? hb[2 * k - 1].w : 0.f;
    const float by = (2 * k < J) ? hb[2 * k].y : 0.f;
    const float bw = (2 * k < J) ? hb[2 * k].w : 0.f;
    hmY[k] = pack2(ay, by);
    hmW[k] = pack2(aw, bw);
  }

  // v prefetch, depth 2.
  const float* vp = v2 + (size_t)y * WW + x0;
  float4 vb0 = *reinterpret_cast<const float4*>(vp);
  float4 vb1 = *reinterpret_cast<const float4*>(vp + VSTR);

  int tb = ty * PAIRS + 2 * tx + QC;  // dword index within a channel tile

  #pragma unroll 1
  for (int i = 0; i < KFS; ++i) {
    const float4 v4 = vb0;
    vb0 = vb1;
    const int ip = (i + 2 <= KFS - 1) ? i + 2 : KFS - 1;
    vb1 = *reinterpret_cast<const float4*>(vp + (size_t)ip * VSTR);

    #pragma unroll
    for (int c = 0; c < NC; ++c) {
      uint32_t ev[NEV];
      #pragma unroll
      for (int k = 0; k < NEV; ++k) ev[k] = tile[c * CTILE + tb + k];

      float hz0 = 0.f, hz1 = 0.f, hz2 = 0.f, hz3 = 0.f;
      #pragma unroll
      for (int k = 0; k < NHE; ++k) hz0 = fdot2(ev[k], heX[k], hz0);
      #pragma unroll
      for (int k = 0; k < NHM; ++k) hz1 = fdot2(ev[k], hmY[k], hz1);
      #pragma unroll
      for (int k = 1; k <= (J + 1) / 2; ++k) hz2 = fdot2(ev[k], heZ[k - 1], hz2);
      #pragma unroll
      for (int k = 1; k <= (J + 2) / 2; ++k) hz3 = fdot2(ev[k], hmW[k - 1], hz3);

      acc[c][0] = fmaf(v4.x, hz0, acc[c][0]);
      acc[c][1] = fmaf(v4.y, hz1, acc[c][1]);
      acc[c][2] = fmaf(v4.z, hz2, acc[c][2]);
      acc[c][3] = fmaf(v4.w, hz3, acc[c][3]);
    }
    tb += PAIRS;
  }
}

__global__ __launch_bounds__(NTHREADS, 2)
void sepconv_kernel(const float* __restrict__ in1, const float* __restrict__ in2,
                    const float* __restrict__ in3, float* __restrict__ out) {
  __shared__ uint32_t tile[NC * CTILE];  // 62,640 B: all 3 channels, f16 pairs

  const int t = threadIdx.x;
  const int tx = t & (NTX - 1);
  const int ty = t >> 5;
  const int x0t = blockIdx.x * TW;
  const int y0t = blockIdx.y * TH;
  const int b = blockIdx.z;
  const int x0 = x0t + tx * PX;
  const int y = y0t + ty;

  const float* in1b = in1 + (size_t)b * NC * HP * WP;
  const float* v2 = in2 + (size_t)b * KFS * HH * WW;
  const float* h3 = in3 + (size_t)b * KFS * HH * WW;

  // Stage all 3 channel tiles once: f32 global -> f16 pairs in LDS (linear).
  constexpr int NU = NC * NROWS * QPR;  // 15486 pair-units
  for (int e = t; e < NU; e += NTHREADS) {
    const int c = e / (NROWS * QPR);
    const int rem = e - c * (NROWS * QPR);
    const int r = rem / QPR;
    const int q = rem - r * QPR;
    const float2 g = *reinterpret_cast<const float2*>(
        in1b + ((size_t)c * HP + y0t + r) * WP + x0t + 2 * q);
    tile[c * CTILE + r * PAIRS + q] = pack2(g.x, g.y);
  }
  __syncthreads();

  float acc[NC][PX];
  #pragma unroll
  for (int c = 0; c < NC; ++c)
    #pragma unroll
    for (int p = 0; p < PX; ++p) acc[c][p] = 0.f;

  run_pass<0, 18>(tile, v2, h3, acc, y, x0, tx, ty);
  run_pass<18, 16>(tile, v2, h3, acc, y, x0, tx, ty);
  run_pass<34, 17>(tile, v2, h3, acc, y, x0, tx, ty);

  float* outb = out + (size_t)b * NC * HH * WW;
  #pragma unroll
  for (int c = 0; c < NC; ++c) {
    float4 o;
    o.x = acc[c][0]; o.y = acc[c][1]; o.z = acc[c][2]; o.w = acc[c][3];
    *reinterpret_cast<float4*>(outb + ((size_t)c * HH + y) * WW + x0) = o;
  }
}

}  // namespace

extern "C" void kernel_launch(void* const* d_in, const int* in_sizes, int n_in,
                              void* d_out, int out_size, void* d_ws, size_t ws_size,
                              hipStream_t stream) {
  const float* in1 = (const float*)d_in[0];
  const float* in2 = (const float*)d_in[1];
  const float* in3 = (const float*)d_in[2];
  float* out = (float*)d_out;

  dim3 grid(WW / TW, HH / TH, NB);
  sepconv_kernel<<<grid, NTHREADS, 0, stream>>>(in1, in2, in3, out);
}

// Round 5
// 112.716 us; speedup vs baseline: 4.0799x; 1.0786x over previous
//
#include <hip/hip_runtime.h>
#include <cstdint>

namespace {

typedef _Float16 half2v __attribute__((ext_vector_type(2)));
typedef unsigned int uint2v __attribute__((ext_vector_type(2)));

constexpr int KFS = 51;
constexpr int NB = 2, NC = 3, HH = 512, WW = 512;
constexpr int HP = HH + KFS - 1;   // 562
constexpr int WP = WW + KFS - 1;   // 562
constexpr int TW = 128, TH = 8, PX = 4;
constexpr int NTX = TW / PX;          // 32
constexpr int NTHREADS = NTX * TH;    // 256
constexpr int TILEW = TW + KFS - 1;   // 178 input cols per tile
constexpr int NROWS = TH + KFS - 1;   // 58 input rows per tile
constexpr int QPR = TILEW / 2;        // 89 f16-pairs per row
constexpr int PAIRS = 90;             // row stride in dwords (even)
constexpr int CTILE = NROWS * PAIRS;  // 5220 dwords per channel (even)
constexpr size_t VSTR = (size_t)HH * WW;

__device__ __forceinline__ uint32_t pack2(float a, float b) {
  half2v p;
  p.x = (_Float16)a;  // RNE
  p.y = (_Float16)b;
  return __builtin_bit_cast(uint32_t, p);
}

__device__ __forceinline__ float fdot2(uint32_t a, uint32_t b, float c) {
#if defined(__has_builtin) && __has_builtin(__builtin_amdgcn_fdot2)
  return __builtin_amdgcn_fdot2(__builtin_bit_cast(half2v, a),
                                __builtin_bit_cast(half2v, b), c, false);
#else
  float r;
  asm("v_dot2_f32_f16 %0, %1, %2, %3" : "=v"(r) : "v"(a), "v"(b), "v"(c));
  return r;
#endif
}

// Pass over taps j = JC..JC+J-1 (JC multiple of 4 -> pair base even -> b64 LDS).
// Window pairs ev[k] = (w[2k], w[2k+1]) relative to col base 4*tx+JC.
//   p=0: ev[k] . (hx[2k],   hx[2k+1])  k=0..NHE-1
//   p=1: ev[k] . (hy[2k-1], hy[2k])    k=0..NHM-1
//   p=2: ev[k] . (hz[2k-2], hz[2k-1])  k=1..NHE
//   p=3: ev[k] . (hw[2k-3], hw[2k-2])  k=1..NHM
template <int JC, int J>
__device__ __forceinline__ void run_pass(const uint32_t* __restrict__ tile,
                                         const float* __restrict__ v2,
                                         const float* __restrict__ h3,
                                         float (&acc)[NC][PX],
                                         int y, int x0, int tx, int ty) {
  constexpr int NHE = (J + 1) / 2;
  constexpr int NHM = (J + 2) / 2;
  constexpr int NPAIR = NHM + 1;        // highest ev index used is NHM
  constexpr int NEV2 = (NPAIR + 1) / 2; // uint2 (b64) loads per (i, c)
  constexpr int QC = JC / 2;            // even by construction
  static_assert((QC & 1) == 0, "pair base must be even for b64");

  // Build packed h registers (once per pass).
  float4 hb[J];
  #pragma unroll
  for (int j = 0; j < J; ++j)
    hb[j] = *reinterpret_cast<const float4*>(h3 + ((size_t)(JC + j) * HH + y) * WW + x0);

  uint32_t heX[NHE], heZ[NHE], hmY[NHM], hmW[NHM];
  #pragma unroll
  for (int k = 0; k < NHE; ++k) {
    const float ax = hb[2 * k].x, az = hb[2 * k].z;
    const float bx = (2 * k + 1 < J) ? hb[2 * k + 1].x : 0.f;
    const float bz = (2 * k + 1 < J) ? hb[2 * k + 1].z : 0.f;
    heX[k] = pack2(ax, bx);
    heZ[k] = pack2(az, bz);
  }
  #pragma unroll
  for (int k = 0; k < NHM; ++k) {
    const float ay = (2 * k - 1 >= 0) ? hb[2 * k - 1].y : 0.f;
    const float aw = (2 * k - 1 >= 0) ? hb[2 * k - 1].w : 0.f;
    const float by = (2 * k < J) ? hb[2 * k].y : 0.f;
    const float bw = (2 * k < J) ? hb[2 * k].w : 0.f;
    hmY[k] = pack2(ay, by);
    hmW[k] = pack2(aw, bw);
  }

  // v prefetch, depth 3, statically rotated via 3x-unrolled body.
  const float* vp = v2 + (size_t)y * WW + x0;
  float4 vr0 = *reinterpret_cast<const float4*>(vp);
  float4 vr1 = *reinterpret_cast<const float4*>(vp + VSTR);
  float4 vr2 = *reinterpret_cast<const float4*>(vp + 2 * VSTR);

  int tb = ty * PAIRS + 2 * tx + QC;  // even dword index within a channel tile

  auto step = [&](int i, float4& vslot) {
    const float4 v4 = vslot;
    const int ip = (i + 3 < KFS) ? i + 3 : KFS - 1;
    vslot = *reinterpret_cast<const float4*>(vp + (size_t)ip * VSTR);

    #pragma unroll
    for (int c = 0; c < NC; ++c) {
      const uint2v* wp2 = reinterpret_cast<const uint2v*>(tile + c * CTILE + tb);
      uint32_t ev[2 * NEV2];
      #pragma unroll
      for (int k = 0; k < NEV2; ++k) {
        const uint2v q = wp2[k];  // ds_read_b64, offset folds to immediate
        ev[2 * k] = q.x;
        ev[2 * k + 1] = q.y;
      }

      float hz0 = 0.f, hz1 = 0.f, hz2 = 0.f, hz3 = 0.f;
      #pragma unroll
      for (int k = 0; k < NHE; ++k) hz0 = fdot2(ev[k], heX[k], hz0);
      #pragma unroll
      for (int k = 0; k < NHM; ++k) hz1 = fdot2(ev[k], hmY[k], hz1);
      #pragma unroll
      for (int k = 1; k <= NHE; ++k) hz2 = fdot2(ev[k], heZ[k - 1], hz2);
      #pragma unroll
      for (int k = 1; k <= NHM; ++k) hz3 = fdot2(ev[k], hmW[k - 1], hz3);

      acc[c][0] = fmaf(v4.x, hz0, acc[c][0]);
      acc[c][1] = fmaf(v4.y, hz1, acc[c][1]);
      acc[c][2] = fmaf(v4.z, hz2, acc[c][2]);
      acc[c][3] = fmaf(v4.w, hz3, acc[c][3]);
    }
    tb += PAIRS;
  };

  #pragma unroll 1
  for (int ii = 0; ii < KFS / 3; ++ii) {
    step(3 * ii + 0, vr0);
    step(3 * ii + 1, vr1);
    step(3 * ii + 2, vr2);
  }
}

__global__ __launch_bounds__(NTHREADS, 2)
void sepconv_kernel(const float* __restrict__ in1, const float* __restrict__ in2,
                    const float* __restrict__ in3, float* __restrict__ out) {
  __shared__ uint32_t tile[NC * CTILE];  // 62,640 B: 3 channels, f16 pairs

  const int t = threadIdx.x;
  const int tx = t & (NTX - 1);
  const int ty = t >> 5;
  const int x0t = blockIdx.x * TW;
  const int y0t = blockIdx.y * TH;
  const int b = blockIdx.z;
  const int x0 = x0t + tx * PX;
  const int y = y0t + ty;

  const float* in1b = in1 + (size_t)b * NC * HP * WP;
  const float* v2 = in2 + (size_t)b * KFS * HH * WW;
  const float* h3 = in3 + (size_t)b * KFS * HH * WW;

  // Stage all 3 channel tiles once: f32 global -> f16 pairs in LDS (linear).
  constexpr int NU = NC * NROWS * QPR;  // 15486 pair-units
  for (int e = t; e < NU; e += NTHREADS) {
    const int c = e / (NROWS * QPR);
    const int rem = e - c * (NROWS * QPR);
    const int r = rem / QPR;
    const int q = rem - r * QPR;
    const float2 g = *reinterpret_cast<const float2*>(
        in1b + ((size_t)c * HP + y0t + r) * WP + x0t + 2 * q);
    tile[c * CTILE + r * PAIRS + q] = pack2(g.x, g.y);
  }
  __syncthreads();

  float acc[NC][PX];
  #pragma unroll
  for (int c = 0; c < NC; ++c)
    #pragma unroll
    for (int p = 0; p < PX; ++p) acc[c][p] = 0.f;

  run_pass<0, 16>(tile, v2, h3, acc, y, x0, tx, ty);
  run_pass<16, 16>(tile, v2, h3, acc, y, x0, tx, ty);
  run_pass<32, 19>(tile, v2, h3, acc, y, x0, tx, ty);

  float* outb = out + (size_t)b * NC * HH * WW;
  #pragma unroll
  for (int c = 0; c < NC; ++c) {
    float4 o;
    o.x = acc[c][0]; o.y = acc[c][1]; o.z = acc[c][2]; o.w = acc[c][3];
    *reinterpret_cast<float4*>(outb + ((size_t)c * HH + y) * WW + x0) = o;
  }
}

}  // namespace

extern "C" void kernel_launch(void* const* d_in, const int* in_sizes, int n_in,
                              void* d_out, int out_size, void* d_ws, size_t ws_size,
                              hipStream_t stream) {
  const float* in1 = (const float*)d_in[0];
  const float* in2 = (const float*)d_in[1];
  const float* in3 = (const float*)d_in[2];
  float* out = (float*)d_out;

  dim3 grid(WW / TW, HH / TH, NB);
  sepconv_kernel<<<grid, NTHREADS, 0, stream>>>(in1, in2, in3, out);
}